// Round 15
// baseline (88.078 us; speedup 1.0000x reference)
//
#include <hip/hip_runtime.h>
#include <stdint.h>

#define NCLS 80
#define BGI 80
#define BB 16
#define NGT 32
#define MM 33600
#define EPSF 1e-9f
#define CAPL 256       // per-(pair,level) candidate cap (expected ~105 max)
#define NSCAN 5632     // 512 pairs * 11 chunks
#define NZ4 10752000   // B*M*80/4 float4 of score tensor
#define ZPB 1910       // float4 per zero block (5632*1910 >= NZ4)

// IoU exactly mirroring reference pairwise_iou op order; no FMA contraction.
__device__ __forceinline__ float iou_f(const float4 b1, const float4 b2) {
#pragma clang fp contract(off)
  float ltx = fmaxf(b1.x, b2.x);
  float lty = fmaxf(b1.y, b2.y);
  float rbx = fminf(b1.z, b2.z);
  float rby = fminf(b1.w, b2.w);
  float iw = fmaxf(rbx - ltx, 0.0f);
  float ih = fmaxf(rby - lty, 0.0f);
  float inter = iw * ih;
  float a1 = (b1.z - b1.x) * (b1.w - b1.y);
  float a2 = (b2.z - b2.x) * (b2.w - b2.y);
  return inter / (a1 + a2 - inter + EPSF);
}

// P0: anchor centers (reference op order) + zero pk and cc.
__global__ __launch_bounds__(256) void k_prep(
    const float4* __restrict__ anchors, float2* __restrict__ centers,
    unsigned int* __restrict__ pk, unsigned int* __restrict__ cc) {
#pragma clang fp contract(off)
  const int i = blockIdx.x * 256 + threadIdx.x;
  if (i < MM) {
    const float4 ab = anchors[i];
    centers[i] = make_float2((ab.x + ab.z) * 0.5f, (ab.y + ab.w) * 0.5f);
  }
  pk[i] = 0u;
  if (i < 512 * 3) cc[i] = 0u;
}

// K1: 11264 x 256-thread blocks; type = (bid>>8)&1 (alternates per
// round-robin round over CU slots -> fine-grained scan/store mixing).
//  scan block (one of 11 chunks of one pair): load chunk centers as float4,
//  compute dist = sqrtf(d2) (reference rounding), cache in registers;
//  16x16-lane group minima -> LDS -> T = 9th-of-16 (valid global bound for
//  ANY subset partition: its 9 smallest group-minima are 9 distinct elements
//  <= T, so the global 9th-smallest K9 <= T; every true top-9 element x has
//  dist(x) <= K9 <= T and is collected by its owner chunk). Register sweep
//  pushes keys (distbits<<32|idx) to per-(pair,lev) global buffers.
//  zero block: fill 1910 float4 of the score tensor.
__global__ __launch_bounds__(256) void k_main(
    const float2* __restrict__ centers, const float4* __restrict__ gtb,
    const float* __restrict__ maskgt, unsigned int* __restrict__ cc,
    unsigned long long* __restrict__ cand, float4* __restrict__ zscores) {
#pragma clang fp contract(off)
  const int tid = threadIdx.x;
  const int bid = (int)blockIdx.x;
  const int sid = (bid & 255) | ((bid >> 9) << 8);  // index within type

  if ((bid >> 8) & 1) {  // ---- zero-fill block
    const float4 zero4 = make_float4(0.f, 0.f, 0.f, 0.f);
    const int base = sid * ZPB;
#pragma unroll
    for (int it = 0; it < 8; ++it) {
      const int idx = it * 256 + tid;
      const int g2 = base + idx;
      if (idx < ZPB && g2 < NZ4) zscores[g2] = zero4;
    }
    return;
  }

  // ---- scan block
  const int pair = sid / 11;         // magic-mul
  const int c = sid - pair * 11;
  if (maskgt[pair] == 0.0f) return;  // masked gt contributes nothing

  int lev, start, len4;  // len4 = #float4 (2 centers each)
  if (c < 8)       { lev = 0; start = c * 3200;              len4 = 1600; }
  else if (c < 10) { lev = 1; start = 25600 + (c - 8) * 3200; len4 = 1600; }
  else             { lev = 2; start = 32000;                 len4 = 800;  }

  const float4 gb = gtb[pair];
  const float gcx = (gb.x + gb.z) * 0.5f;
  const float gcy = (gb.y + gb.w) * 0.5f;
  const float4* c4 = (const float4*)centers + (start >> 1);

  __shared__ float s_gmin[16];

  float dd0[7], dd1[7];
  float gm = 3.4e38f;
#pragma unroll
  for (int it = 0; it < 7; ++it) {
    const int p = it * 256 + tid;
    float d0 = 3.4e38f, d1 = 3.4e38f;
    if (p < len4) {
      const float4 two = c4[p];
      const float dx0 = gcx - two.x, dy0 = gcy - two.y;
      const float dx1 = gcx - two.z, dy1 = gcy - two.w;
      d0 = sqrtf(dx0 * dx0 + dy0 * dy0);  // reference rounding
      d1 = sqrtf(dx1 * dx1 + dy1 * dy1);
    }
    dd0[it] = d0;
    dd1[it] = d1;
    gm = fminf(gm, fminf(d0, d1));
  }
  // 16-lane group minima (xor masks 8,4,2,1 stay within 16-lane groups)
#pragma unroll
  for (int s = 8; s >= 1; s >>= 1)
    gm = fminf(gm, __shfl_xor(gm, s, 64));
  if ((tid & 15) == 0) s_gmin[tid >> 4] = gm;
  __syncthreads();  // the only barrier

  // T = 9th smallest of 16 group minima (computed redundantly; 256 thr only)
  float T = 0.0f;
#pragma unroll
  for (int cw = 0; cw < 16; ++cw) {
    const float v = s_gmin[cw];
    int r = 0;
#pragma unroll
    for (int q = 0; q < 16; ++q) {
      const float o = s_gmin[q];
      r += (o < v) || (o == v && q < cw);
    }
    if (r == 8) T = v;  // unique rank -> exactly one cw
  }

  // register sweep: push candidates (no memory re-read)
  unsigned int* myc = &cc[pair * 3 + lev];
  unsigned long long* mybuf = cand + (size_t)(pair * 3 + lev) * CAPL;
#pragma unroll
  for (int it = 0; it < 7; ++it) {
    const int p = it * 256 + tid;
    if (dd0[it] <= T) {
      const unsigned int slot = atomicAdd(myc, 1u);
      if (slot < CAPL)
        mybuf[slot] = ((unsigned long long)__float_as_uint(dd0[it]) << 32) |
                      (unsigned long long)(unsigned int)(start + 2 * p);
    }
    if (dd1[it] <= T) {
      const unsigned int slot = atomicAdd(myc, 1u);
      if (slot < CAPL)
        mybuf[slot] = ((unsigned long long)__float_as_uint(dd1[it]) << 32) |
                      (unsigned long long)(unsigned int)(start + 2 * p + 1);
    }
  }
}

// K2: one 64-thread (1-wave) block per pair. Exact rank-select of top-9 per
// level from the global candidate pool (keys unique via idx low bits; equal
// dist -> smaller index, matching lax.top_k), then the proven epilogue:
// candidate IoUs, mean+std(ddof=1) threshold, inside-gt test, pk scatter.
__global__ __launch_bounds__(64) void k_sel(
    const float4* __restrict__ anchors, const float2* __restrict__ centers,
    const float4* __restrict__ gtb, const float* __restrict__ maskgt,
    const unsigned int* __restrict__ cc,
    const unsigned long long* __restrict__ cand,
    unsigned int* __restrict__ pk) {
#pragma clang fp contract(off)
  const int pair = blockIdx.x;
  if (maskgt[pair] == 0.0f) return;
  const int b = pair >> 5;
  const int g = pair & 31;
  const int lane = threadIdx.x;
  const float4 gb = gtb[pair];

  __shared__ unsigned long long keys[CAPL];
  __shared__ unsigned long long winners[27];

#pragma unroll
  for (int lev = 0; lev < 3; ++lev) {
    const int m = (int)min(cc[pair * 3 + lev], (unsigned int)CAPL);
    const unsigned long long* src = cand + (size_t)(pair * 3 + lev) * CAPL;
    for (int i = lane; i < m; i += 64) keys[i] = src[i];
    __syncthreads();
    for (int i = lane; i < m; i += 64) {
      const unsigned long long k = keys[i];
      int r = 0;
      for (int q = 0; q < m; ++q) r += (keys[q] < k);
      if (r < 9) winners[lev * 9 + r] = k;  // each chunk pushed >=9 -> m>=9
    }
    __syncthreads();
  }

  unsigned int mycand = 0;
  if (lane < 27) mycand = (unsigned int)(winners[lane] & 0xffffffffu);

  float ov = 0.0f;
  bool inside = false;
  if (lane < 27) {
    const float4 ab = anchors[mycand];
    ov = iou_f(gb, ab);
    const float2 ac = centers[mycand];
    const float m1 = fminf(fminf(ac.x - gb.x, ac.y - gb.y),
                           fminf(gb.z - ac.x, gb.w - ac.y));
    inside = m1 > EPSF;
  }
  float s = (lane < 27) ? ov : 0.0f;
#pragma unroll
  for (int sft = 32; sft >= 1; sft >>= 1) s += __shfl_xor(s, sft, 64);
  const float mean = s / 27.0f;
  float dev = (lane < 27) ? (ov - mean) : 0.0f;
  float s2 = dev * dev;
#pragma unroll
  for (int sft = 32; sft >= 1; sft >>= 1) s2 += __shfl_xor(s2, sft, 64);
  const float thr = mean + sqrtf(s2 / 26.0f);

  if (lane < 27 && inside && ov > thr) {
    // packed: cnt in bits[31:20], sum of g in bits[19:0].
    // <=32 adds: cnt<=32, g-sum<=992 -> no overflow; cnt==1 -> low bits = g.
    atomicAdd(&pk[b * MM + (int)mycand], (1u << 20) | (unsigned int)g);
  }
}

// B1 sparse: per (b,a) resolve assignment; labels/bbox/fg + ONE scalar score
// per fg anchor (score tensor pre-zeroed by k_main's fill blocks).
__global__ __launch_bounds__(256) void k_out(
    const float4* __restrict__ anchors, const float4* __restrict__ gtb,
    const int* __restrict__ glabels, const float4* __restrict__ predb,
    const unsigned int* __restrict__ pk,
    float* __restrict__ out_labels, float4* __restrict__ out_bbox,
    float* __restrict__ out_fg, float* __restrict__ out_scores) {
  const int a = blockIdx.x * 256 + threadIdx.x;
  if (a >= MM) return;
  const int b = blockIdx.y;
  const int i = b * MM + a;
  const unsigned int p = pk[i];
  const unsigned int c = p >> 20;
  int g = 0;
  const bool fg = (c != 0u);
  if (c == 1u) {
    g = (int)(p & 0xFFFFFu);
  } else if (c > 1u) {
    // reference: column replaced by one_hot(argmax_g overlaps) — includes
    // masked gts; first-max tie-break like jnp.argmax.
    const float4 ab = anchors[a];
    float best = -1.0f;
    for (int gg = 0; gg < NGT; ++gg) {
      const float ovv = iou_f(gtb[b * NGT + gg], ab);
      if (ovv > best) { best = ovv; g = gg; }
    }
  }
  const int lbl = fg ? glabels[b * NGT + g] : BGI;
  out_labels[i] = (float)lbl;
  out_bbox[i] = gtb[b * NGT + g];  // !fg -> g==0 (argmax of zeros)
  out_fg[i] = fg ? 1.0f : 0.0f;
  if (fg) {
    const float io = iou_f(gtb[b * NGT + g], predb[i]);
    out_scores[(size_t)i * NCLS + lbl] = io;  // rest of row stays zero
  }
}

extern "C" void kernel_launch(void* const* d_in, const int* in_sizes, int n_in,
                              void* d_out, int out_size, void* d_ws, size_t ws_size,
                              hipStream_t stream) {
  // Identify inputs by size (robust to how the n_level tuple is passed).
  const float* anchors = nullptr;
  const float* gtb = nullptr;
  const int* glab = nullptr;
  const float* maskgt = nullptr;
  const float* predb = nullptr;
  int seen512 = 0;
  for (int i = 0; i < n_in; ++i) {
    const int sz = in_sizes[i];
    if (sz == 134400 && !anchors) anchors = (const float*)d_in[i];
    else if (sz == 2048 && !gtb) gtb = (const float*)d_in[i];
    else if (sz == 512) {
      if (seen512++ == 0) glab = (const int*)d_in[i];
      else maskgt = (const float*)d_in[i];
    } else if (sz == 2150400 && !predb) predb = (const float*)d_in[i];
  }
  if (!anchors || !gtb || !glab || !maskgt || !predb) return;  // defensive

  float* out = (float*)d_out;
  float* out_labels = out;                          // [B*M]
  float4* out_bbox = (float4*)(out + 537600);       // [B*M][4]
  float* out_scores = out + 2688000;                // [B*M][80]
  float* out_fg = out + 45696000;                   // [B*M]

  // ws layout (5.6 MB): pk | centers | cc | cand
  unsigned int* pk = (unsigned int*)d_ws;               // [B*M]
  float2* centers = (float2*)(pk + 537600);             // [M]
  unsigned int* cc = (unsigned int*)(centers + MM);     // [512*3]
  unsigned long long* cand =
      (unsigned long long*)(cc + 512 * 3);              // [512*3][CAPL]

  k_prep<<<dim3(2100), dim3(256), 0, stream>>>(
      (const float4*)anchors, centers, pk, cc);

  k_main<<<dim3(2 * NSCAN), dim3(256), 0, stream>>>(
      centers, (const float4*)gtb, maskgt, cc, cand, (float4*)out_scores);

  k_sel<<<dim3(512), dim3(64), 0, stream>>>(
      (const float4*)anchors, centers, (const float4*)gtb, maskgt, cc, cand,
      pk);

  k_out<<<dim3(132, BB), dim3(256), 0, stream>>>(
      (const float4*)anchors, (const float4*)gtb, glab, (const float4*)predb,
      pk, out_labels, out_bbox, out_fg, out_scores);
}

// Round 16
// 60.274 us; speedup vs baseline: 1.4613x; 1.4613x over previous
//
#include <hip/hip_runtime.h>
#include <stdint.h>

#define NCLS 80
#define BGI 80
#define BB 16
#define NGT 32
#define MM 33600
#define EPSF 1e-9f
#define CAP 1024
#define ZPB 21000  // float4 per zero block: 512*21000 == 10752000 == B*M*80/4

// IoU exactly mirroring reference pairwise_iou op order; no FMA contraction.
__device__ __forceinline__ float iou_f(const float4 b1, const float4 b2) {
#pragma clang fp contract(off)
  float ltx = fmaxf(b1.x, b2.x);
  float lty = fmaxf(b1.y, b2.y);
  float rbx = fminf(b1.z, b2.z);
  float rby = fminf(b1.w, b2.w);
  float iw = fmaxf(rbx - ltx, 0.0f);
  float ih = fmaxf(rby - lty, 0.0f);
  float inter = iw * ih;
  float a1 = (b1.z - b1.x) * (b1.w - b1.y);
  float a2 = (b2.z - b2.x) * (b2.w - b2.y);
  return inter / (a1 + a2 - inter + EPSF);
}

// P0: precompute anchor centers (same op order as reference anchor_points)
// and zero the packed (cnt|g-sum) scatter array. 2100*256 == 537600 exact.
__global__ __launch_bounds__(256) void k_prep(
    const float4* __restrict__ anchors, float2* __restrict__ centers,
    unsigned int* __restrict__ pk) {
#pragma clang fp contract(off)
  const int i = blockIdx.x * 256 + threadIdx.x;
  if (i < MM) {
    const float4 ab = anchors[i];
    centers[i] = make_float2((ab.x + ab.z) * 0.5f, (ab.y + ab.w) * 0.5f);
  }
  pk[i] = 0u;
}

// One level of bound-then-rank with register-cached squared distances:
//  pass1: float4 loads (2 centers each), cache d2 in static-indexed unrolled
//         arrays; per-thread min -> 16 wave minima -> LDS; wave 0 computes
//         T = sqrt(9th smallest). Valid bound for ANY 16-way partition: its
//         9 smallest partition-minima are 9 distinct elements <= T => K9 <= T.
//         Monotone (correctly-rounded) sqrt commutes with min/rank.
//  sweep: pure register pass — dist = sqrtf(d2) (reference rounding),
//         push keys (distbits<<32|idx) with dist<=T. OOB slots hold 3.4e38
//         -> sqrt ~ 1.8e19 > T, never pushed.
//  rank:  rank = #smaller keys; keys unique via idx low bits -> exact top-9
//         with lax.top_k tie semantics (equal dist -> smaller index).
// Same 4-barrier-per-level pattern as the 54.1us-proven R12 kernel.
template <int ITERS, int START, int LEN4>
__device__ __forceinline__ void level_scan(
    const float4* __restrict__ c4all, const float gcx, const float gcy,
    const int tid, const int lane, const int wid,
    unsigned long long* __restrict__ buf, unsigned long long* __restrict__ wslot,
    float* __restrict__ s_wmin, float* __restrict__ s_T,
    unsigned int* __restrict__ s_cnt) {
#pragma clang fp contract(off)
  const float4* c4 = c4all + (START >> 1);
  float d20[ITERS], d21[ITERS];
  float mymin = 3.4e38f;
#pragma unroll
  for (int it = 0; it < ITERS; ++it) {
    const int p = it * 1024 + tid;
    float a = 3.4e38f, b = 3.4e38f;
    if (p < LEN4) {
      const float4 two = c4[p];
      const float dx0 = gcx - two.x, dy0 = gcy - two.y;
      const float dx1 = gcx - two.z, dy1 = gcy - two.w;
      a = dx0 * dx0 + dy0 * dy0;
      b = dx1 * dx1 + dy1 * dy1;
    }
    d20[it] = a;
    d21[it] = b;
    mymin = fminf(mymin, fminf(a, b));
  }
#pragma unroll
  for (int s = 32; s >= 1; s >>= 1)
    mymin = fminf(mymin, __shfl_xor(mymin, s, 64));
  if (lane == 0) s_wmin[wid] = mymin;
  if (tid == 0) *s_cnt = 0u;
  __syncthreads();

  // T = sqrt(9th smallest of the 16 squared wave minima), wave 0 only
  if (wid == 0 && lane < 16) {
    const float v = s_wmin[lane];
    int r = 0;
#pragma unroll
    for (int q = 0; q < 16; ++q) {
      const float o = s_wmin[q];
      r += (o < v) || (o == v && q < lane);
    }
    if (r == 8) *s_T = sqrtf(v);  // unique rank -> exactly one lane
  }
  __syncthreads();
  const float T = *s_T;

  // register sweep: no memory re-read
#pragma unroll
  for (int it = 0; it < ITERS; ++it) {
    const int p = it * 1024 + tid;
    const float dist0 = sqrtf(d20[it]);
    const float dist1 = sqrtf(d21[it]);
    if (dist0 <= T) {
      const unsigned int q = atomicAdd(s_cnt, 1u);
      if (q < CAP)
        buf[q] = ((unsigned long long)__float_as_uint(dist0) << 32) |
                 (unsigned long long)(unsigned int)(START + 2 * p);
    }
    if (dist1 <= T) {
      const unsigned int q = atomicAdd(s_cnt, 1u);
      if (q < CAP)
        buf[q] = ((unsigned long long)__float_as_uint(dist1) << 32) |
                 (unsigned long long)(unsigned int)(START + 2 * p + 1);
    }
  }
  __syncthreads();

  const int m = (int)min(*s_cnt, (unsigned int)CAP);
  // rank-select: exactly 9 winners (keys unique -> ranks unique)
  for (int i = tid; i < m; i += 1024) {
    const unsigned long long k = buf[i];
    int r = 0;
    for (int q = 0; q < m; ++q) r += (buf[q] < k);
    if (r < 9) wslot[r] = k;
  }
  __syncthreads();
}

// K1 hybrid: 1024 uniform 1024-thread blocks; type = (blockIdx>>8)&1.
// Blocks j and j+256 share a CU slot and have different types -> each CU
// co-hosts one scan block + one zero-writer (R12-verified layout).
__global__ __launch_bounds__(1024) void k_topk(
    const float4* __restrict__ anchors, const float2* __restrict__ centers,
    const float4* __restrict__ gtb, const float* __restrict__ maskgt,
    unsigned int* __restrict__ pk, float4* __restrict__ zscores) {
#pragma clang fp contract(off)
  const int tid = threadIdx.x;
  const int bid = (int)blockIdx.x;

  if ((bid >> 8) & 1) {  // ---- zero-writer block
    const int zb = (bid & 255) | ((bid >> 9) << 8);  // 0..511
    float4* z = zscores + (size_t)zb * ZPB;
    const float4 zero4 = make_float4(0.f, 0.f, 0.f, 0.f);
#pragma unroll
    for (int it = 0; it < 21; ++it) {  // 21*1024 covers 21000 (predicated)
      const int idx = it * 1024 + tid;
      if (idx < ZPB) z[idx] = zero4;
    }
    return;
  }

  const int pair = (bid & 255) | ((bid >> 9) << 8);  // 0..511 == b*32+g
  if (maskgt[pair] == 0.0f) return;       // masked gt contributes nothing
  const int b = pair >> 5;
  const int g = pair & 31;
  const int lane = tid & 63;
  const int wid = tid >> 6;
  const float4 gb = gtb[pair];
  const float gcx = (gb.x + gb.z) * 0.5f;
  const float gcy = (gb.y + gb.w) * 0.5f;

  __shared__ unsigned long long buf[CAP];
  __shared__ unsigned long long winners[27];
  __shared__ float s_wmin[16];
  __shared__ float s_T;
  __shared__ unsigned int s_cnt;

  const float4* c4all = (const float4*)centers;  // 16B-aligned

  level_scan<13, 0, 12800>(c4all, gcx, gcy, tid, lane, wid,
                           buf, &winners[0], s_wmin, &s_T, &s_cnt);
  level_scan<4, 25600, 3200>(c4all, gcx, gcy, tid, lane, wid,
                             buf, &winners[9], s_wmin, &s_T, &s_cnt);
  level_scan<1, 32000, 800>(c4all, gcx, gcy, tid, lane, wid,
                            buf, &winners[18], s_wmin, &s_T, &s_cnt);

  if (wid != 0) return;  // wave 0 finishes; no more barriers

  unsigned int mycand = 0;
  if (lane < 27) mycand = (unsigned int)(winners[lane] & 0xffffffffu);

  // candidate IoUs + inside-gt test (lanes 0..26)
  float ov = 0.0f;
  bool inside = false;
  if (lane < 27) {
    const float4 ab = anchors[mycand];
    ov = iou_f(gb, ab);
    const float2 ac = centers[mycand];
    const float m1 = fminf(fminf(ac.x - gb.x, ac.y - gb.y),
                           fminf(gb.z - ac.x, gb.w - ac.y));
    inside = m1 > EPSF;
  }
  // thr = mean + std(ddof=1) over the 27 gathered IoUs
  float s = (lane < 27) ? ov : 0.0f;
#pragma unroll
  for (int sft = 32; sft >= 1; sft >>= 1) s += __shfl_xor(s, sft, 64);
  const float mean = s / 27.0f;
  float dev = (lane < 27) ? (ov - mean) : 0.0f;
  float s2 = dev * dev;
#pragma unroll
  for (int sft = 32; sft >= 1; sft >>= 1) s2 += __shfl_xor(s2, sft, 64);
  const float thr = mean + sqrtf(s2 / 26.0f);

  if (lane < 27 && inside && ov > thr) {
    // packed: cnt in bits[31:20], sum of g in bits[19:0].
    // <=32 adds: cnt<=32, g-sum<=992 -> no field overflow; cnt==1 -> low=g.
    atomicAdd(&pk[b * MM + (int)mycand], (1u << 20) | (unsigned int)g);
  }
}

// B1 sparse: per (b,a) resolve assignment; write labels/bbox/fg and — since
// the score tensor is pre-zeroed by k_topk's zero blocks — ONE scalar score
// per fg anchor.
__global__ __launch_bounds__(256) void k_out(
    const float4* __restrict__ anchors, const float4* __restrict__ gtb,
    const int* __restrict__ glabels, const float4* __restrict__ predb,
    const unsigned int* __restrict__ pk,
    float* __restrict__ out_labels, float4* __restrict__ out_bbox,
    float* __restrict__ out_fg, float* __restrict__ out_scores) {
  const int a = blockIdx.x * 256 + threadIdx.x;
  if (a >= MM) return;
  const int b = blockIdx.y;
  const int i = b * MM + a;
  const unsigned int p = pk[i];
  const unsigned int c = p >> 20;
  int g = 0;
  const bool fg = (c != 0u);
  if (c == 1u) {
    g = (int)(p & 0xFFFFFu);
  } else if (c > 1u) {
    // reference: column replaced by one_hot(argmax_g overlaps) — includes
    // masked gts; first-max tie-break like jnp.argmax.
    const float4 ab = anchors[a];
    float best = -1.0f;
    for (int gg = 0; gg < NGT; ++gg) {
      const float ovv = iou_f(gtb[b * NGT + gg], ab);
      if (ovv > best) { best = ovv; g = gg; }
    }
  }
  const int lbl = fg ? glabels[b * NGT + g] : BGI;
  out_labels[i] = (float)lbl;
  out_bbox[i] = gtb[b * NGT + g];  // !fg -> g==0 (argmax of zeros)
  out_fg[i] = fg ? 1.0f : 0.0f;
  if (fg) {
    const float io = iou_f(gtb[b * NGT + g], predb[i]);
    out_scores[(size_t)i * NCLS + lbl] = io;  // rest of row stays zero
  }
}

extern "C" void kernel_launch(void* const* d_in, const int* in_sizes, int n_in,
                              void* d_out, int out_size, void* d_ws, size_t ws_size,
                              hipStream_t stream) {
  // Identify inputs by size (robust to how the n_level tuple is passed).
  const float* anchors = nullptr;
  const float* gtb = nullptr;
  const int* glab = nullptr;
  const float* maskgt = nullptr;
  const float* predb = nullptr;
  int seen512 = 0;
  for (int i = 0; i < n_in; ++i) {
    const int sz = in_sizes[i];
    if (sz == 134400 && !anchors) anchors = (const float*)d_in[i];
    else if (sz == 2048 && !gtb) gtb = (const float*)d_in[i];
    else if (sz == 512) {
      if (seen512++ == 0) glab = (const int*)d_in[i];
      else maskgt = (const float*)d_in[i];
    } else if (sz == 2150400 && !predb) predb = (const float*)d_in[i];
  }
  if (!anchors || !gtb || !glab || !maskgt || !predb) return;  // defensive

  float* out = (float*)d_out;
  float* out_labels = out;                          // [B*M]
  float4* out_bbox = (float4*)(out + 537600);       // [B*M][4]
  float* out_scores = out + 2688000;                // [B*M][80]
  float* out_fg = out + 45696000;                   // [B*M]

  unsigned int* pk = (unsigned int*)d_ws;           // [B*M] packed cnt|gsum
  float2* centers = (float2*)(pk + 537600);         // [M], 16B-aligned

  k_prep<<<dim3(2100), dim3(256), 0, stream>>>(
      (const float4*)anchors, centers, pk);

  k_topk<<<dim3(1024), dim3(1024), 0, stream>>>(
      (const float4*)anchors, centers, (const float4*)gtb, maskgt, pk,
      (float4*)out_scores);

  k_out<<<dim3(132, BB), dim3(256), 0, stream>>>(
      (const float4*)anchors, (const float4*)gtb, glab, (const float4*)predb,
      pk, out_labels, out_bbox, out_fg, out_scores);
}

// Round 17
// 54.046 us; speedup vs baseline: 1.6297x; 1.1152x over previous
//
#include <hip/hip_runtime.h>
#include <stdint.h>

#define NCLS 80
#define BGI 80
#define BB 16
#define NGT 32
#define MM 33600
#define EPSF 1e-9f
#define CAP 1024
#define ZPB 21000  // float4 per zero block: 512*21000 == 10752000 == B*M*80/4

// IoU exactly mirroring reference pairwise_iou op order; no FMA contraction.
__device__ __forceinline__ float iou_f(const float4 b1, const float4 b2) {
#pragma clang fp contract(off)
  float ltx = fmaxf(b1.x, b2.x);
  float lty = fmaxf(b1.y, b2.y);
  float rbx = fminf(b1.z, b2.z);
  float rby = fminf(b1.w, b2.w);
  float iw = fmaxf(rbx - ltx, 0.0f);
  float ih = fmaxf(rby - lty, 0.0f);
  float inter = iw * ih;
  float a1 = (b1.z - b1.x) * (b1.w - b1.y);
  float a2 = (b2.z - b2.x) * (b2.w - b2.y);
  return inter / (a1 + a2 - inter + EPSF);
}

// P0: precompute anchor centers (same op order as reference anchor_points)
// and zero the packed (cnt|g-sum) scatter array. 2100*256 == 537600 exact.
__global__ __launch_bounds__(256) void k_prep(
    const float4* __restrict__ anchors, float2* __restrict__ centers,
    unsigned int* __restrict__ pk) {
#pragma clang fp contract(off)
  const int i = blockIdx.x * 256 + threadIdx.x;
  if (i < MM) {
    const float4 ab = anchors[i];
    centers[i] = make_float2((ab.x + ab.z) * 0.5f, (ab.y + ab.w) * 0.5f);
  }
  pk[i] = 0u;
}

// K1 hybrid: 1024 uniform 1024-thread blocks; type = (blockIdx>>8)&1.
// Blocks j and j+256 share a CU slot under both plausible mappings and have
// different types -> each CU co-hosts one scan block + one zero-writer.
//
// Top-k = bound-then-rank, float4 scan (2 centers/iter):
//  pass1: per-thread min of SQUARED dist -> 16 wave minima; wave 0 computes
//         T = sqrt(9th smallest). Valid for ANY 16-way partition: the 9
//         smallest partition-minima are 9 distinct elements <= T => K9 <= T.
//         Monotone sqrt commutes with min/rank.
//  pass2: per-element dist = sqrt(d2) (reference rounding); collect keys
//         (distbits<<32|idx) with dist<=T into LDS.
//  rank:  rank = #smaller keys; keys unique via idx low bits -> exact top-9
//         with lax.top_k tie semantics (equal dist -> smaller index).
__global__ __launch_bounds__(1024) void k_topk(
    const float4* __restrict__ anchors, const float2* __restrict__ centers,
    const float4* __restrict__ gtb, const float* __restrict__ maskgt,
    unsigned int* __restrict__ pk, float4* __restrict__ zscores) {
#pragma clang fp contract(off)
  const int tid = threadIdx.x;
  const int bid = (int)blockIdx.x;

  if ((bid >> 8) & 1) {  // ---- zero-writer block
    const int zb = (bid & 255) | ((bid >> 9) << 8);  // 0..511
    float4* z = zscores + (size_t)zb * ZPB;
    const float4 zero4 = make_float4(0.f, 0.f, 0.f, 0.f);
#pragma unroll
    for (int it = 0; it < 21; ++it) {  // 21*1024 covers 21000 (predicated)
      const int idx = it * 1024 + tid;
      if (idx < ZPB) z[idx] = zero4;
    }
    return;
  }

  const int pair = (bid & 255) | ((bid >> 9) << 8);  // 0..511 == b*32+g
  if (maskgt[pair] == 0.0f) return;       // masked gt contributes nothing
  const int b = pair >> 5;
  const int g = pair & 31;
  const int lane = tid & 63;
  const int wid = tid >> 6;
  const float4 gb = gtb[pair];
  const float gcx = (gb.x + gb.z) * 0.5f;
  const float gcy = (gb.y + gb.w) * 0.5f;

  __shared__ unsigned long long buf[CAP];
  __shared__ unsigned long long winners[27];
  __shared__ float s_wmin[16];
  __shared__ float s_T;
  __shared__ unsigned int s_cnt;

  const int LSTART[3] = {0, 25600, 32000};
  const int LLEN[3]   = {25600, 6400, 1600};

#pragma unroll
  for (int lev = 0; lev < 3; ++lev) {
    const int start = LSTART[lev];
    const int len2 = LLEN[lev] >> 1;  // pairs of centers
    const float4* c4 = (const float4*)(centers + start);  // 16B-aligned

    // pass 1: branch-free per-thread min of squared distance, 2 centers/load
    float mymin = 3.4e38f;
    for (int p = tid; p < len2; p += 1024) {
      const float4 two = c4[p];
      const float dx0 = gcx - two.x, dy0 = gcy - two.y;
      const float dx1 = gcx - two.z, dy1 = gcy - two.w;
      mymin = fminf(mymin,
                    fminf(dx0 * dx0 + dy0 * dy0, dx1 * dx1 + dy1 * dy1));
    }
#pragma unroll
    for (int s = 32; s >= 1; s >>= 1)
      mymin = fminf(mymin, __shfl_xor(mymin, s, 64));
    if (lane == 0) s_wmin[wid] = mymin;
    if (tid == 0) s_cnt = 0u;
    __syncthreads();

    // T = sqrt(9th smallest of the 16 squared wave minima), wave 0 only
    if (wid == 0 && lane < 16) {
      const float v = s_wmin[lane];
      int r = 0;
#pragma unroll
      for (int q = 0; q < 16; ++q) {
        const float o = s_wmin[q];
        r += (o < v) || (o == v && q < lane);
      }
      if (r == 8) s_T = sqrtf(v);  // unique rank -> exactly one lane
    }
    __syncthreads();
    const float T = s_T;

    // pass 2: collect candidates with per-element sqrt'd dist
    for (int p = tid; p < len2; p += 1024) {
      const float4 two = c4[p];
      const float dx0 = gcx - two.x, dy0 = gcy - two.y;
      const float dx1 = gcx - two.z, dy1 = gcy - two.w;
      const float dist0 = sqrtf(dx0 * dx0 + dy0 * dy0);
      const float dist1 = sqrtf(dx1 * dx1 + dy1 * dy1);
      if (dist0 <= T) {
        const unsigned int q = atomicAdd(&s_cnt, 1u);
        if (q < CAP)
          buf[q] = ((unsigned long long)__float_as_uint(dist0) << 32) |
                   (unsigned long long)(unsigned int)(start + 2 * p);
      }
      if (dist1 <= T) {
        const unsigned int q = atomicAdd(&s_cnt, 1u);
        if (q < CAP)
          buf[q] = ((unsigned long long)__float_as_uint(dist1) << 32) |
                   (unsigned long long)(unsigned int)(start + 2 * p + 1);
      }
    }
    __syncthreads();

    const int m = (int)min(s_cnt, (unsigned int)CAP);
    // rank-select: exactly 9 winners (keys unique -> ranks unique)
    for (int i = tid; i < m; i += 1024) {
      const unsigned long long k = buf[i];
      int r = 0;
      for (int q = 0; q < m; ++q) r += (buf[q] < k);
      if (r < 9) winners[lev * 9 + r] = k;
    }
    __syncthreads();
  }

  if (wid != 0) return;  // wave 0 finishes; no more barriers

  unsigned int mycand = 0;
  if (lane < 27) mycand = (unsigned int)(winners[lane] & 0xffffffffu);

  // candidate IoUs + inside-gt test (lanes 0..26)
  float ov = 0.0f;
  bool inside = false;
  if (lane < 27) {
    const float4 ab = anchors[mycand];
    ov = iou_f(gb, ab);
    const float2 ac = centers[mycand];
    const float m1 = fminf(fminf(ac.x - gb.x, ac.y - gb.y),
                           fminf(gb.z - ac.x, gb.w - ac.y));
    inside = m1 > EPSF;
  }
  // thr = mean + std(ddof=1) over the 27 gathered IoUs
  float s = (lane < 27) ? ov : 0.0f;
#pragma unroll
  for (int sft = 32; sft >= 1; sft >>= 1) s += __shfl_xor(s, sft, 64);
  const float mean = s / 27.0f;
  float dev = (lane < 27) ? (ov - mean) : 0.0f;
  float s2 = dev * dev;
#pragma unroll
  for (int sft = 32; sft >= 1; sft >>= 1) s2 += __shfl_xor(s2, sft, 64);
  const float thr = mean + sqrtf(s2 / 26.0f);

  if (lane < 27 && inside && ov > thr) {
    // packed: cnt in bits[31:20], sum of g in bits[19:0].
    // <=32 adds: cnt<=32, g-sum<=992 -> no field overflow; cnt==1 -> low=g.
    atomicAdd(&pk[b * MM + (int)mycand], (1u << 20) | (unsigned int)g);
  }
}

// B1 sparse: per (b,a) resolve assignment; write labels/bbox/fg and — since
// the score tensor is pre-zeroed by k_topk's zero blocks — ONE scalar score
// per fg anchor.
__global__ __launch_bounds__(256) void k_out(
    const float4* __restrict__ anchors, const float4* __restrict__ gtb,
    const int* __restrict__ glabels, const float4* __restrict__ predb,
    const unsigned int* __restrict__ pk,
    float* __restrict__ out_labels, float4* __restrict__ out_bbox,
    float* __restrict__ out_fg, float* __restrict__ out_scores) {
  const int a = blockIdx.x * 256 + threadIdx.x;
  if (a >= MM) return;
  const int b = blockIdx.y;
  const int i = b * MM + a;
  const unsigned int p = pk[i];
  const unsigned int c = p >> 20;
  int g = 0;
  const bool fg = (c != 0u);
  if (c == 1u) {
    g = (int)(p & 0xFFFFFu);
  } else if (c > 1u) {
    // reference: column replaced by one_hot(argmax_g overlaps) — includes
    // masked gts; first-max tie-break like jnp.argmax.
    const float4 ab = anchors[a];
    float best = -1.0f;
    for (int gg = 0; gg < NGT; ++gg) {
      const float ovv = iou_f(gtb[b * NGT + gg], ab);
      if (ovv > best) { best = ovv; g = gg; }
    }
  }
  const int lbl = fg ? glabels[b * NGT + g] : BGI;
  out_labels[i] = (float)lbl;
  out_bbox[i] = gtb[b * NGT + g];  // !fg -> g==0 (argmax of zeros)
  out_fg[i] = fg ? 1.0f : 0.0f;
  if (fg) {
    const float io = iou_f(gtb[b * NGT + g], predb[i]);
    out_scores[(size_t)i * NCLS + lbl] = io;  // rest of row stays zero
  }
}

extern "C" void kernel_launch(void* const* d_in, const int* in_sizes, int n_in,
                              void* d_out, int out_size, void* d_ws, size_t ws_size,
                              hipStream_t stream) {
  // Identify inputs by size (robust to how the n_level tuple is passed).
  const float* anchors = nullptr;
  const float* gtb = nullptr;
  const int* glab = nullptr;
  const float* maskgt = nullptr;
  const float* predb = nullptr;
  int seen512 = 0;
  for (int i = 0; i < n_in; ++i) {
    const int sz = in_sizes[i];
    if (sz == 134400 && !anchors) anchors = (const float*)d_in[i];
    else if (sz == 2048 && !gtb) gtb = (const float*)d_in[i];
    else if (sz == 512) {
      if (seen512++ == 0) glab = (const int*)d_in[i];
      else maskgt = (const float*)d_in[i];
    } else if (sz == 2150400 && !predb) predb = (const float*)d_in[i];
  }
  if (!anchors || !gtb || !glab || !maskgt || !predb) return;  // defensive

  float* out = (float*)d_out;
  float* out_labels = out;                          // [B*M]
  float4* out_bbox = (float4*)(out + 537600);       // [B*M][4]
  float* out_scores = out + 2688000;                // [B*M][80]
  float* out_fg = out + 45696000;                   // [B*M]

  unsigned int* pk = (unsigned int*)d_ws;           // [B*M] packed cnt|gsum
  float2* centers = (float2*)(pk + 537600);         // [M], 16B-aligned

  k_prep<<<dim3(2100), dim3(256), 0, stream>>>(
      (const float4*)anchors, centers, pk);

  k_topk<<<dim3(1024), dim3(1024), 0, stream>>>(
      (const float4*)anchors, centers, (const float4*)gtb, maskgt, pk,
      (float4*)out_scores);

  k_out<<<dim3(132, BB), dim3(256), 0, stream>>>(
      (const float4*)anchors, (const float4*)gtb, glab, (const float4*)predb,
      pk, out_labels, out_bbox, out_fg, out_scores);
}